// Round 1
// baseline (590.552 us; speedup 1.0000x reference)
//
#include <hip/hip_runtime.h>

#define BB 32
#define NN 16384
#define SS 8
#define DD 64
#define HH 128

typedef __attribute__((ext_vector_type(4))) float f4;
typedef __attribute__((ext_vector_type(8))) short short8;

__device__ __forceinline__ unsigned short f2bf(float f) {
  unsigned int u = __float_as_uint(f);
  unsigned int r = (u + 0x7fffu + ((u >> 16) & 1u)) >> 16;
  return (unsigned short)r;
}
__device__ __forceinline__ float bf2f(unsigned short h) {
  return __uint_as_float(((unsigned int)h) << 16);
}
__device__ __forceinline__ void unpk(unsigned int u, float& lo, float& hi) {
  lo = __uint_as_float(u << 16);
  hi = __uint_as_float(u & 0xffff0000u);
}
__device__ __forceinline__ short bfs(float f) { return (short)f2bf(f); }

__device__ __forceinline__ short8 ldw(const float* p) {
  f4 w0 = *(const f4*)p;
  f4 w1 = *(const f4*)(p + 4);
  short8 r;
#pragma unroll
  for (int j = 0; j < 4; ++j) { r[j] = bfs(w0[j]); r[j + 4] = bfs(w1[j]); }
  return r;
}

// ---------------------------------------------------------------------------
// proj: K = LN(x)@Wk^T, V = LN(x)@Wv^T  (bf16 out), fused slots init.
// blocks [0,8192): 64 rows each (4 waves x 16-row strips). blocks [8192,8256): slots init.
// MFMA: D = A*B, A-frag = W rows (m=d), B-frag = LN(x) rows (col=n).
// C/D: col=lane&15 (=n), row=quad*4+reg (=d-in-tile) -> lane stores 4 contiguous d.
// ---------------------------------------------------------------------------
__global__ void __launch_bounds__(256) proj_kernel(
    const float* __restrict__ x, const float* __restrict__ gin, const float* __restrict__ bin,
    const float* __restrict__ Wk, const float* __restrict__ Wv,
    unsigned short* __restrict__ Ko, unsigned short* __restrict__ Vo,
    const float* __restrict__ noise, const float* __restrict__ mu,
    const float* __restrict__ lsig, float* __restrict__ slots)
{
  const int blk = blockIdx.x;
  if (blk >= 8192) {  // slots = mu + exp(log_sigma) * noise
    int idx = (blk - 8192) * 256 + threadIdx.x;  // [0,16384)
    slots[idx] = mu[idx & 511] + __expf(lsig[idx & 511]) * noise[idx];
    return;
  }
  const int tid = threadIdx.x, wave = tid >> 6, lane = tid & 63;
  const int l15 = lane & 15, quad = lane >> 4;
  const size_t row = (size_t)blk * 64 + wave * 16 + l15;  // global n; also the n-col this lane feeds

  const float* xr = x + row * 64 + quad * 8;
  f4 x00 = *(const f4*)xr;         // k = quad*8 + 0..3
  f4 x01 = *(const f4*)(xr + 4);   // k = quad*8 + 4..7
  f4 x10 = *(const f4*)(xr + 32);  // k = 32 + quad*8 + 0..3
  f4 x11 = *(const f4*)(xr + 36);

  float sm = 0.f, sq = 0.f;
#pragma unroll
  for (int j = 0; j < 4; ++j) {
    float v0 = x00[j], v1 = x01[j], v2 = x10[j], v3 = x11[j];
    sm += v0 + v1 + v2 + v3;
    sq += v0 * v0 + v1 * v1 + v2 * v2 + v3 * v3;
  }
  sm += __shfl_xor(sm, 16); sq += __shfl_xor(sq, 16);
  sm += __shfl_xor(sm, 32); sq += __shfl_xor(sq, 32);
  const float mean = sm * (1.f / 64.f);
  const float var = sq * (1.f / 64.f) - mean * mean;
  const float rstd = rsqrtf(var + 1e-5f);

  const int k0 = quad * 8;
  f4 g00 = *(const f4*)(gin + k0),      g01 = *(const f4*)(gin + k0 + 4);
  f4 g10 = *(const f4*)(gin + k0 + 32), g11 = *(const f4*)(gin + k0 + 36);
  f4 b00 = *(const f4*)(bin + k0),      b01 = *(const f4*)(bin + k0 + 4);
  f4 b10 = *(const f4*)(bin + k0 + 32), b11 = *(const f4*)(bin + k0 + 36);

  short8 a0, a1;
#pragma unroll
  for (int j = 0; j < 4; ++j) {
    a0[j]     = bfs((x00[j] - mean) * rstd * g00[j] + b00[j]);
    a0[j + 4] = bfs((x01[j] - mean) * rstd * g01[j] + b01[j]);
    a1[j]     = bfs((x10[j] - mean) * rstd * g10[j] + b10[j]);
    a1[j + 4] = bfs((x11[j] - mean) * rstd * g11[j] + b11[j]);
  }

#pragma unroll
  for (int dt = 0; dt < 4; ++dt) {
    const int d = dt * 16 + l15;  // A-frag row m
    const float* wkp = Wk + d * 64 + quad * 8;
    const float* wvp = Wv + d * 64 + quad * 8;
    short8 wk0 = ldw(wkp), wk1 = ldw(wkp + 32);
    short8 wv0 = ldw(wvp), wv1 = ldw(wvp + 32);
    f4 ak = {0.f, 0.f, 0.f, 0.f}, av = {0.f, 0.f, 0.f, 0.f};
    ak = __builtin_amdgcn_mfma_f32_16x16x32_bf16(wk0, a0, ak, 0, 0, 0);
    ak = __builtin_amdgcn_mfma_f32_16x16x32_bf16(wk1, a1, ak, 0, 0, 0);
    av = __builtin_amdgcn_mfma_f32_16x16x32_bf16(wv0, a0, av, 0, 0, 0);
    av = __builtin_amdgcn_mfma_f32_16x16x32_bf16(wv1, a1, av, 0, 0, 0);
    // lane holds D[row=quad*4+reg][col=l15] -> d = dt*16+quad*4+reg, n = row (this lane's row)
    unsigned int kp0 = (unsigned int)f2bf(ak[0]) | ((unsigned int)f2bf(ak[1]) << 16);
    unsigned int kp1 = (unsigned int)f2bf(ak[2]) | ((unsigned int)f2bf(ak[3]) << 16);
    unsigned int vp0 = (unsigned int)f2bf(av[0]) | ((unsigned int)f2bf(av[1]) << 16);
    unsigned int vp1 = (unsigned int)f2bf(av[2]) | ((unsigned int)f2bf(av[3]) << 16);
    *(uint2*)(Ko + row * 64 + dt * 16 + quad * 4) = make_uint2(kp0, kp1);
    *(uint2*)(Vo + row * 64 + dt * 16 + quad * 4) = make_uint2(vp0, vp1);
  }
}

// ---------------------------------------------------------------------------
// reduce: per iteration. logits = K.q, softmax over S, accumulate
// Wpart[s][d] = sum_n P[n,s]*V[n,d], cpart[s] = sum_n P[n,s].
// grid 1024 = 32 batches x 32 chunks(512 rows). block 256 = 4 waves x 128 rows.
// EPS term dropped: EPS*N = 1.6e-4 vs csum ~ 2048 -> relative 8e-8, far below tol.
// ---------------------------------------------------------------------------
__global__ void __launch_bounds__(256) reduce_kernel(
    const unsigned short* __restrict__ K, const unsigned short* __restrict__ V,
    const float* __restrict__ slots,
    const float* __restrict__ gs, const float* __restrict__ bs,
    const float* __restrict__ Wq,
    float* __restrict__ Wpart, float* __restrict__ cpart)
{
  __shared__ float sln[8][64];
  __shared__ __align__(16) unsigned short qld[8][64];
  __shared__ __align__(16) unsigned short Vld[4][16][72];  // pad 72 -> conflict-free u16 reads
  __shared__ __align__(16) unsigned short Pld[4][16][8];
  __shared__ float red[4][512];
  __shared__ float cred[4][8];

  const int tid = threadIdx.x, wave = tid >> 6, lane = tid & 63;
  const int b = blockIdx.x >> 5, ch = blockIdx.x & 31;

  // q = LN(slots) @ Wq^T * D^-0.5  (built redundantly per block; tiny)
  if (wave == 0) {
#pragma unroll
    for (int s = 0; s < 8; ++s) {
      float v = slots[((b << 3) + s) * 64 + lane];
      float sm = v, sq = v * v;
#pragma unroll
      for (int m = 1; m < 64; m <<= 1) { sm += __shfl_xor(sm, m); sq += __shfl_xor(sq, m); }
      float mean = sm * (1.f / 64.f);
      float var = sq * (1.f / 64.f) - mean * mean;
      sln[s][lane] = (v - mean) * rsqrtf(var + 1e-5f) * gs[lane] + bs[lane];
    }
  }
  __syncthreads();
  {
    const int s = tid >> 5, d0 = (tid & 31) * 2;
    float acc0 = 0.f, acc1 = 0.f;
    const float* w0 = Wq + d0 * 64;
    for (int k = 0; k < 64; ++k) { float sv = sln[s][k]; acc0 += sv * w0[k]; acc1 += sv * w0[64 + k]; }
    qld[s][d0] = f2bf(acc0 * 0.125f);
    qld[s][d0 + 1] = f2bf(acc1 * 0.125f);
  }
  __syncthreads();

  const size_t base = (size_t)b * NN * 64;
  const unsigned short* Kb = K + base;
  const unsigned short* Vb = V + base;
  const int r = lane >> 2, c16 = (lane & 3) * 16;
  float Wacc[8], cacc[8];
#pragma unroll
  for (int s = 0; s < 8; ++s) { Wacc[s] = 0.f; cacc[s] = 0.f; }
  const int nbase = ch * 512 + wave * 128;

  for (int g = 0; g < 8; ++g) {
    const int n0 = nbase + (g << 4);
    const unsigned short* kp = Kb + (size_t)(n0 + r) * 64 + c16;
    const unsigned short* vp = Vb + (size_t)(n0 + r) * 64 + c16;
    uint4 ka = *(const uint4*)kp,  kb2 = *(const uint4*)(kp + 8);
    uint4 va = *(const uint4*)vp,  vb2 = *(const uint4*)(vp + 8);
    *(uint4*)&Vld[wave][r][c16] = va;
    *(uint4*)&Vld[wave][r][c16 + 8] = vb2;
    float kf[16];
    unpk(ka.x, kf[0], kf[1]);   unpk(ka.y, kf[2], kf[3]);
    unpk(ka.z, kf[4], kf[5]);   unpk(ka.w, kf[6], kf[7]);
    unpk(kb2.x, kf[8], kf[9]);  unpk(kb2.y, kf[10], kf[11]);
    unpk(kb2.z, kf[12], kf[13]);unpk(kb2.w, kf[14], kf[15]);

    float lg[8];
#pragma unroll
    for (int s = 0; s < 8; ++s) {
      uint4 qa = *(const uint4*)&qld[s][c16];
      uint4 qb = *(const uint4*)&qld[s][c16 + 8];
      float qa_, qb_; float acc = 0.f;
      unpk(qa.x, qa_, qb_); acc += kf[0] * qa_ + kf[1] * qb_;
      unpk(qa.y, qa_, qb_); acc += kf[2] * qa_ + kf[3] * qb_;
      unpk(qa.z, qa_, qb_); acc += kf[4] * qa_ + kf[5] * qb_;
      unpk(qa.w, qa_, qb_); acc += kf[6] * qa_ + kf[7] * qb_;
      unpk(qb.x, qa_, qb_); acc += kf[8] * qa_ + kf[9] * qb_;
      unpk(qb.y, qa_, qb_); acc += kf[10] * qa_ + kf[11] * qb_;
      unpk(qb.z, qa_, qb_); acc += kf[12] * qa_ + kf[13] * qb_;
      unpk(qb.w, qa_, qb_); acc += kf[14] * qa_ + kf[15] * qb_;
      lg[s] = acc;
    }
#pragma unroll
    for (int s = 0; s < 8; ++s) { lg[s] += __shfl_xor(lg[s], 1); lg[s] += __shfl_xor(lg[s], 2); }
    // softmax over S=8 (replicated x4 per row; bitwise identical across replicas)
    float mx = lg[0];
#pragma unroll
    for (int s = 1; s < 8; ++s) mx = fmaxf(mx, lg[s]);
    float se = 0.f;
#pragma unroll
    for (int s = 0; s < 8; ++s) { lg[s] = __expf(lg[s] - mx); se += lg[s]; }
    float inv = 1.f / se;
#pragma unroll
    for (int s = 0; s < 8; ++s) { lg[s] *= inv; cacc[s] += lg[s]; }
    if ((lane & 3) == 0) {
      uint4 pw;
      pw.x = (unsigned int)f2bf(lg[0]) | ((unsigned int)f2bf(lg[1]) << 16);
      pw.y = (unsigned int)f2bf(lg[2]) | ((unsigned int)f2bf(lg[3]) << 16);
      pw.z = (unsigned int)f2bf(lg[4]) | ((unsigned int)f2bf(lg[5]) << 16);
      pw.w = (unsigned int)f2bf(lg[6]) | ((unsigned int)f2bf(lg[7]) << 16);
      *(uint4*)&Pld[wave][r][0] = pw;
    }
    // same-wave LDS write->read is in-order on the DS pipe; buffers are per-wave -> no barrier
#pragma unroll
    for (int n = 0; n < 16; ++n) {
      uint4 p = *(const uint4*)&Pld[wave][n][0];
      float vf = bf2f(Vld[wave][n][lane]);
      float p0, p1;
      unpk(p.x, p0, p1); Wacc[0] += p0 * vf; Wacc[1] += p1 * vf;
      unpk(p.y, p0, p1); Wacc[2] += p0 * vf; Wacc[3] += p1 * vf;
      unpk(p.z, p0, p1); Wacc[4] += p0 * vf; Wacc[5] += p1 * vf;
      unpk(p.w, p0, p1); Wacc[6] += p0 * vf; Wacc[7] += p1 * vf;
    }
  }

  // csum: reduce over the 16 row-groups (xor 4,8,16,32); replicas live in distinct classes
#pragma unroll
  for (int m = 4; m < 64; m <<= 1) {
#pragma unroll
    for (int s = 0; s < 8; ++s) cacc[s] += __shfl_xor(cacc[s], m);
  }
#pragma unroll
  for (int s = 0; s < 8; ++s) red[wave][s * 64 + lane] = Wacc[s];
  if (lane == 0) {
#pragma unroll
    for (int s = 0; s < 8; ++s) cred[wave][s] = cacc[s];
  }
  __syncthreads();
  for (int i = tid; i < 512; i += 256)
    Wpart[(size_t)blockIdx.x * 512 + i] = red[0][i] + red[1][i] + red[2][i] + red[3][i];
  if (tid < 8)
    cpart[blockIdx.x * 8 + tid] = cred[0][tid] + cred[1][tid] + cred[2][tid] + cred[3][tid];
}

// ---------------------------------------------------------------------------
// update: per (b,s), 1 wave (lane = feature d). GRU + LN + MLP + residual.
// ---------------------------------------------------------------------------
__global__ void __launch_bounds__(64) update_kernel(
    const float* __restrict__ Wpart, const float* __restrict__ cpart,
    const float* __restrict__ slots, float* __restrict__ out,
    const float* __restrict__ W_ih, const float* __restrict__ W_hh,
    const float* __restrict__ b_ih, const float* __restrict__ b_hh,
    const float* __restrict__ g_mlp, const float* __restrict__ b_mlp,
    const float* __restrict__ W1, const float* __restrict__ b1,
    const float* __restrict__ W2, const float* __restrict__ b2)
{
  const int bs = blockIdx.x;
  const int b = bs >> 3, s = bs & 7;
  const int l = threadIdx.x;
  __shared__ float u_sh[64], sp_sh[64], uln_sh[64], h_sh[128];

  float wsum = 0.f;
  for (int c = 0; c < 32; ++c) wsum += Wpart[(size_t)((b * 32 + c) * 8 + s) * 64 + l];
  float cs = 0.f;
  for (int c = 0; c < 32; ++c) cs += cpart[(b * 32 + c) * 8 + s];
  const float u = wsum / cs;
  const float sp = slots[(b * 8 + s) * 64 + l];
  u_sh[l] = u; sp_sh[l] = sp;
  __syncthreads();

  float gi[3], gh[3];
#pragma unroll
  for (int part = 0; part < 3; ++part) {
    const int j = part * 64 + l;
    float accI = b_ih[j], accH = b_hh[j];
    const float* wi = W_ih + j * 64;
    const float* wh = W_hh + j * 64;
    for (int k = 0; k < 64; ++k) { accI += u_sh[k] * wi[k]; accH += sp_sh[k] * wh[k]; }
    gi[part] = accI; gh[part] = accH;
  }
  const float rg = 1.f / (1.f + __expf(-(gi[0] + gh[0])));
  const float zg = 1.f / (1.f + __expf(-(gi[1] + gh[1])));
  const float ng = tanhf(gi[2] + rg * gh[2]);
  const float upd = (1.f - zg) * ng + zg * sp;

  float sm = upd, sq = upd * upd;
#pragma unroll
  for (int m = 1; m < 64; m <<= 1) { sm += __shfl_xor(sm, m); sq += __shfl_xor(sq, m); }
  const float mean = sm * (1.f / 64.f);
  const float var = sq * (1.f / 64.f) - mean * mean;
  uln_sh[l] = (upd - mean) * rsqrtf(var + 1e-5f) * g_mlp[l] + b_mlp[l];
  __syncthreads();

#pragma unroll
  for (int part = 0; part < 2; ++part) {
    const int j = part * 64 + l;
    float acc = b1[j];
    const float* w1 = W1 + j * 64;
    for (int k = 0; k < 64; ++k) acc += uln_sh[k] * w1[k];
    h_sh[j] = fmaxf(acc, 0.f);
  }
  __syncthreads();

  float acc = b2[l];
  const float* w2 = W2 + l * 128;
  for (int k = 0; k < 128; ++k) acc += h_sh[k] * w2[k];
  out[(b * 8 + s) * 64 + l] = upd + acc;
}

// ---------------------------------------------------------------------------
extern "C" void kernel_launch(void* const* d_in, const int* in_sizes, int n_in,
                              void* d_out, int out_size, void* d_ws, size_t ws_size,
                              hipStream_t stream) {
  const float* x       = (const float*)d_in[0];
  const float* noise   = (const float*)d_in[1];
  const float* mu      = (const float*)d_in[2];
  const float* lsig    = (const float*)d_in[3];
  const float* ln_in_g = (const float*)d_in[4];
  const float* ln_in_b = (const float*)d_in[5];
  const float* ln_sl_g = (const float*)d_in[6];
  const float* ln_sl_b = (const float*)d_in[7];
  const float* ln_ml_g = (const float*)d_in[8];
  const float* ln_ml_b = (const float*)d_in[9];
  const float* Wq      = (const float*)d_in[10];
  const float* Wk      = (const float*)d_in[11];
  const float* Wv      = (const float*)d_in[12];
  const float* W_ih    = (const float*)d_in[13];
  const float* W_hh    = (const float*)d_in[14];
  const float* b_ih    = (const float*)d_in[15];
  const float* b_hh    = (const float*)d_in[16];
  const float* W1      = (const float*)d_in[17];
  const float* b1      = (const float*)d_in[18];
  const float* W2      = (const float*)d_in[19];
  const float* b2      = (const float*)d_in[20];

  // ws layout: K bf16 (64MB) | V bf16 (64MB) | slots f32 (64KB) | Wpart f32 x3 | cpart f32 x3
  unsigned short* Kw = (unsigned short*)d_ws;
  unsigned short* Vw = Kw + (size_t)BB * NN * 64;
  float* slots = (float*)(Vw + (size_t)BB * NN * 64);
  float* WpartBase = slots + BB * SS * DD;
  float* cpartBase = WpartBase + (size_t)3 * 1024 * 512;
  // total = 134.2MB + 64KB + 6.3MB + 96KB  (assumed <= ws_size)

  proj_kernel<<<dim3(8256), dim3(256), 0, stream>>>(
      x, ln_in_g, ln_in_b, Wk, Wv, Kw, Vw, noise, mu, lsig, slots);

  for (int it = 0; it < 3; ++it) {
    float* Wp = WpartBase + (size_t)it * 1024 * 512;
    float* cp = cpartBase + (size_t)it * 1024 * 8;
    reduce_kernel<<<dim3(1024), dim3(256), 0, stream>>>(
        Kw, Vw, slots, ln_sl_g, ln_sl_b, Wq, Wp, cp);
    update_kernel<<<dim3(256), dim3(64), 0, stream>>>(
        Wp, cp, slots, (it == 2) ? (float*)d_out : slots,
        W_ih, W_hh, b_ih, b_hh, ln_ml_g, ln_ml_b, W1, b1, W2, b2);
  }
}

// Round 2
// 399.821 us; speedup vs baseline: 1.4770x; 1.4770x over previous
//
#include <hip/hip_runtime.h>

#define BB 32
#define NN 16384

typedef __attribute__((ext_vector_type(4))) float f4;
typedef __attribute__((ext_vector_type(8))) short short8;

__device__ __forceinline__ unsigned int f2bf(float f) {
  unsigned int u = __float_as_uint(f);
  return (u + 0x7fffu + ((u >> 16) & 1u)) >> 16;
}
__device__ __forceinline__ short bfs(float f) { return (short)f2bf(f); }

// ---------------------------------------------------------------------------
// prep: Wk, Wv fp32 -> bf16 (done once; proj then loads b128 directly)
// ---------------------------------------------------------------------------
__global__ void __launch_bounds__(256) prep_kernel(
    const float* __restrict__ Wk, const float* __restrict__ Wv,
    unsigned short* __restrict__ Wkb, unsigned short* __restrict__ Wvb)
{
  int id = blockIdx.x * 256 + threadIdx.x;  // grid 16 -> 4096
  Wkb[id] = (unsigned short)f2bf(Wk[id]);
  Wvb[id] = (unsigned short)f2bf(Wv[id]);
}

// ---------------------------------------------------------------------------
// proj: K[b][n][d] = LN(x)@Wk^T (bf16, n-major), Vt[b][d][n] = (LN(x)@Wv^T)^T
// (bf16, d-major). blocks [0,2048): 256 rows each (4 waves x 16-row strips x
// 4 groups, x prefetched one group ahead). blocks [2048,2112): slots init.
// K: mfma(W,x) -> lane holds 4 consecutive d of one n -> packed 8B store.
// Vt: mfma(x,W) -> lane holds 4 consecutive n of one d -> packed 8B store.
// ---------------------------------------------------------------------------
__global__ void __launch_bounds__(256) proj_kernel(
    const float* __restrict__ x, const float* __restrict__ gin, const float* __restrict__ bin,
    const unsigned short* __restrict__ Wkb, const unsigned short* __restrict__ Wvb,
    unsigned short* __restrict__ Ko, unsigned short* __restrict__ Vt,
    const float* __restrict__ noise, const float* __restrict__ mu,
    const float* __restrict__ lsig, float* __restrict__ slots)
{
  const int blk = blockIdx.x;
  if (blk >= 2048) {  // slots = mu + exp(log_sigma) * noise
    int idx = (blk - 2048) * 256 + threadIdx.x;  // [0,16384)
    slots[idx] = mu[idx & 511] + __expf(lsig[idx & 511]) * noise[idx];
    return;
  }
  const int tid = threadIdx.x, wave = tid >> 6, lane = tid & 63;
  const int l15 = lane & 15, quad = lane >> 4;
  const int b = blk >> 6;                                   // 64 blocks per batch
  const int nstrip = ((blk & 63) << 8) + (wave << 4);       // n-in-batch, strip base
  const size_t row0 = ((size_t)blk << 8) + (wave << 4) + l15;
  const float* xp = x + row0 * 64 + quad * 8;

  const int k0 = quad * 8;
  f4 g0a = *(const f4*)(gin + k0),      g0b = *(const f4*)(gin + k0 + 4);
  f4 g1a = *(const f4*)(gin + k0 + 32), g1b = *(const f4*)(gin + k0 + 36);
  f4 h0a = *(const f4*)(bin + k0),      h0b = *(const f4*)(bin + k0 + 4);
  f4 h1a = *(const f4*)(bin + k0 + 32), h1b = *(const f4*)(bin + k0 + 36);

  f4 c0 = *(const f4*)xp, c1 = *(const f4*)(xp + 4);
  f4 c2 = *(const f4*)(xp + 32), c3 = *(const f4*)(xp + 36);

  for (int g = 0; g < 4; ++g) {
    f4 p0, p1, p2, p3;
    if (g < 3) {  // prefetch next group (64 rows ahead)
      const float* np = xp + (size_t)(g + 1) * 4096;
      p0 = *(const f4*)np;        p1 = *(const f4*)(np + 4);
      p2 = *(const f4*)(np + 32); p3 = *(const f4*)(np + 36);
    }
    float sm = 0.f, sq = 0.f;
#pragma unroll
    for (int j = 0; j < 4; ++j) {
      float v0 = c0[j], v1 = c1[j], v2 = c2[j], v3 = c3[j];
      sm += v0 + v1 + v2 + v3;
      sq += v0 * v0 + v1 * v1 + v2 * v2 + v3 * v3;
    }
    sm += __shfl_xor(sm, 16); sq += __shfl_xor(sq, 16);
    sm += __shfl_xor(sm, 32); sq += __shfl_xor(sq, 32);
    const float mean = sm * (1.f / 64.f);
    const float var = sq * (1.f / 64.f) - mean * mean;
    const float rstd = rsqrtf(var + 1e-5f);

    short8 a0, a1;
#pragma unroll
    for (int j = 0; j < 4; ++j) {
      a0[j]     = bfs((c0[j] - mean) * rstd * g0a[j] + h0a[j]);
      a0[j + 4] = bfs((c1[j] - mean) * rstd * g0b[j] + h0b[j]);
      a1[j]     = bfs((c2[j] - mean) * rstd * g1a[j] + h1a[j]);
      a1[j + 4] = bfs((c3[j] - mean) * rstd * g1b[j] + h1b[j]);
    }

#pragma unroll
    for (int dt = 0; dt < 4; ++dt) {
      const unsigned short* wkp = Wkb + ((dt << 4) + l15) * 64 + k0;
      const unsigned short* wvp = Wvb + ((dt << 4) + l15) * 64 + k0;
      short8 wk0 = *(const short8*)wkp, wk1 = *(const short8*)(wkp + 32);
      short8 wv0 = *(const short8*)wvp, wv1 = *(const short8*)(wvp + 32);
      f4 ak = {0.f, 0.f, 0.f, 0.f}, av = {0.f, 0.f, 0.f, 0.f};
      ak = __builtin_amdgcn_mfma_f32_16x16x32_bf16(wk0, a0, ak, 0, 0, 0);
      ak = __builtin_amdgcn_mfma_f32_16x16x32_bf16(wk1, a1, ak, 0, 0, 0);
      av = __builtin_amdgcn_mfma_f32_16x16x32_bf16(a0, wv0, av, 0, 0, 0);
      av = __builtin_amdgcn_mfma_f32_16x16x32_bf16(a1, wv1, av, 0, 0, 0);
      // K: lane holds K[n=own row][d = dt*16 + quad*4 + reg]
      uint2 kk;
      kk.x = f2bf(ak[0]) | (f2bf(ak[1]) << 16);
      kk.y = f2bf(ak[2]) | (f2bf(ak[3]) << 16);
      *(uint2*)(Ko + (row0 + (size_t)g * 64) * 64 + (dt << 4) + (quad << 2)) = kk;
      // Vt: lane holds V[n = strip + quad*4 + reg][d = dt*16 + l15]
      uint2 vv;
      vv.x = f2bf(av[0]) | (f2bf(av[1]) << 16);
      vv.y = f2bf(av[2]) | (f2bf(av[3]) << 16);
      const int d = (dt << 4) + l15;
      *(uint2*)(Vt + (((size_t)(b << 6) + d) << 14) + nstrip + (g << 6) + (quad << 2)) = vv;
    }
    c0 = p0; c1 = p1; c2 = p2; c3 = p3;
  }
}

// ---------------------------------------------------------------------------
// q: q[b][s][d] = bf16( LN(slots)@Wq^T * D^-0.5 ).  grid 256 = (b,s), block 64.
// ---------------------------------------------------------------------------
__global__ void __launch_bounds__(64) q_kernel(
    const float* __restrict__ slots, const float* __restrict__ gs, const float* __restrict__ bsl,
    const float* __restrict__ Wq, unsigned short* __restrict__ qb)
{
  const int bsi = blockIdx.x, l = threadIdx.x;
  __shared__ float sh[64];
  float v = slots[bsi * 64 + l];
  float sm = v, sq = v * v;
#pragma unroll
  for (int m = 1; m < 64; m <<= 1) { sm += __shfl_xor(sm, m); sq += __shfl_xor(sq, m); }
  float mean = sm * (1.f / 64.f);
  float var = sq * (1.f / 64.f) - mean * mean;
  sh[l] = (v - mean) * rsqrtf(var + 1e-5f) * gs[l] + bsl[l];
  __syncthreads();
  float acc = 0.f;
  const float* w = Wq + l * 64;
  for (int k = 0; k < 64; ++k) acc += sh[k] * w[k];
  qb[bsi * 64 + l] = (unsigned short)f2bf(acc * 0.125f);
}

// ---------------------------------------------------------------------------
// reduce: logits/softmax/PV all-MFMA. grid 1024 = 32 b x 32 chunks(512 rows),
// block 256 = 4 waves x 128 rows. Per wave: 4 units of 32 rows:
//   2x [logits mfma (K as A, q as B) -> softmax via 8-lane butterflies ->
//       P bf16 -> per-wave LDS transpose tile]
//   then P as A-frag (b128), V^T as B-frag (b128 global), 4 PV mfma.
// s = lane&7 (upper 8 cols duplicate s 0..7 -> no garbage anywhere).
// No barrier in main loop (per-wave LDS tile, same-wave DS ordering).
// ---------------------------------------------------------------------------
__global__ void __launch_bounds__(256) reduce_kernel(
    const unsigned short* __restrict__ K, const unsigned short* __restrict__ Vt,
    const unsigned short* __restrict__ qb,
    float* __restrict__ Wpart, float* __restrict__ cpart)
{
  __shared__ __align__(16) unsigned short Pt[4][16][40];  // row 80B: b128-aligned, <=2-way banks
  __shared__ float red[4][512];
  __shared__ float cred[4][8];

  const int tid = threadIdx.x, wave = tid >> 6, lane = tid & 63;
  const int l15 = lane & 15, quad = lane >> 4;
  const int b = blockIdx.x >> 5, ch = blockIdx.x & 31;

  const unsigned short* qrow = qb + (((b << 3) + (l15 & 7)) << 6) + quad * 8;
  short8 qf0 = *(const short8*)qrow;
  short8 qf1 = *(const short8*)(qrow + 32);

  const unsigned short* Kb = K + ((size_t)b << 20);
  const unsigned short* Vb = Vt + ((size_t)b << 20);

  f4 wacc[4];
#pragma unroll
  for (int t = 0; t < 4; ++t) wacc[t] = (f4){0.f, 0.f, 0.f, 0.f};
  float cacc = 0.f;
  const int nb0 = ch * 512 + wave * 128;

  for (int u = 0; u < 4; ++u) {
    const int nb = nb0 + u * 32;
#pragma unroll
    for (int h = 0; h < 2; ++h) {
      const unsigned short* kp = Kb + (size_t)(nb + h * 16 + l15) * 64 + quad * 8;
      short8 kf0 = *(const short8*)kp;
      short8 kf1 = *(const short8*)(kp + 32);
      f4 lg = {0.f, 0.f, 0.f, 0.f};
      lg = __builtin_amdgcn_mfma_f32_16x16x32_bf16(kf0, qf0, lg, 0, 0, 0);
      lg = __builtin_amdgcn_mfma_f32_16x16x32_bf16(kf1, qf1, lg, 0, 0, 0);
      // lane holds lg[n_local = quad*4+reg][s = l15 (dup at 8..15)]
      float p[4];
#pragma unroll
      for (int r2 = 0; r2 < 4; ++r2) {
        float v = lg[r2];
        float mx = v;
        mx = fmaxf(mx, __shfl_xor(mx, 1));
        mx = fmaxf(mx, __shfl_xor(mx, 2));
        mx = fmaxf(mx, __shfl_xor(mx, 4));
        float e = __expf(v - mx);
        float ss = e;
        ss += __shfl_xor(ss, 1);
        ss += __shfl_xor(ss, 2);
        ss += __shfl_xor(ss, 4);
        p[r2] = e * __builtin_amdgcn_rcpf(ss);
        cacc += p[r2];
      }
      unsigned short* pw = &Pt[wave][l15][h * 16 + quad * 4];
      *(unsigned int*)pw = f2bf(p[0]) | (f2bf(p[1]) << 16);
      *(unsigned int*)(pw + 2) = f2bf(p[2]) | (f2bf(p[3]) << 16);
    }
    // P^T now in Pt[s][0..31]; read A-frag: A[m=s=l15][k=n=quad*8+j]
    short8 pf = *(const short8*)&Pt[wave][l15][quad * 8];
#pragma unroll
    for (int t = 0; t < 4; ++t) {
      const unsigned short* vp = Vb + (size_t)((t << 4) + l15) * 16384 + nb + quad * 8;
      short8 vf = *(const short8*)vp;  // B[col=d=t*16+l15][k=n=quad*8+j]
      wacc[t] = __builtin_amdgcn_mfma_f32_16x16x32_bf16(pf, vf, wacc[t], 0, 0, 0);
    }
  }

  // cacc: per-lane sum over its quad's n; reduce across quads (dup s-halves agree)
  cacc += __shfl_xor(cacc, 16);
  cacc += __shfl_xor(cacc, 32);
  if (lane < 8) cred[wave][lane] = cacc;
  // wacc: lane holds W[s = quad*4+reg][d = t*16+l15]; rows 8..15 are dups -> quads 0,1 only
  if (quad < 2) {
#pragma unroll
    for (int t = 0; t < 4; ++t)
#pragma unroll
      for (int r2 = 0; r2 < 4; ++r2)
        red[wave][(quad * 4 + r2) * 64 + (t << 4) + l15] = wacc[t][r2];
  }
  __syncthreads();
  for (int i = tid; i < 512; i += 256)
    Wpart[(size_t)blockIdx.x * 512 + i] = red[0][i] + red[1][i] + red[2][i] + red[3][i];
  if (tid < 8)
    cpart[blockIdx.x * 8 + tid] = cred[0][tid] + cred[1][tid] + cred[2][tid] + cred[3][tid];
}

// ---------------------------------------------------------------------------
// update: per (b,s), 1 wave. GRU + LN + MLP + residual; optionally emits next q.
// ---------------------------------------------------------------------------
__global__ void __launch_bounds__(64) update_kernel(
    const float* __restrict__ Wpart, const float* __restrict__ cpart,
    const float* __restrict__ slots, float* __restrict__ out,
    const float* __restrict__ W_ih, const float* __restrict__ W_hh,
    const float* __restrict__ b_ih, const float* __restrict__ b_hh,
    const float* __restrict__ g_mlp, const float* __restrict__ b_mlp,
    const float* __restrict__ W1, const float* __restrict__ b1,
    const float* __restrict__ W2, const float* __restrict__ b2,
    const float* __restrict__ gs, const float* __restrict__ bsl,
    const float* __restrict__ Wq, unsigned short* __restrict__ qb, int make_q)
{
  const int bs = blockIdx.x;
  const int b = bs >> 3, s = bs & 7;
  const int l = threadIdx.x;
  __shared__ float u_sh[64], sp_sh[64], uln_sh[64], h_sh[128];

  float wsum = 0.f;
  for (int c = 0; c < 32; ++c) wsum += Wpart[(size_t)((b * 32 + c) * 8 + s) * 64 + l];
  float cs = 0.f;
  for (int c = 0; c < 32; ++c) cs += cpart[(b * 32 + c) * 8 + s];
  const float u = wsum / cs;
  const float sp = slots[(b * 8 + s) * 64 + l];
  u_sh[l] = u; sp_sh[l] = sp;
  __syncthreads();

  float gi[3], gh[3];
#pragma unroll
  for (int part = 0; part < 3; ++part) {
    const int j = part * 64 + l;
    float accI = b_ih[j], accH = b_hh[j];
    const float* wi = W_ih + j * 64;
    const float* wh = W_hh + j * 64;
    for (int k = 0; k < 64; ++k) { accI += u_sh[k] * wi[k]; accH += sp_sh[k] * wh[k]; }
    gi[part] = accI; gh[part] = accH;
  }
  const float rg = 1.f / (1.f + __expf(-(gi[0] + gh[0])));
  const float zg = 1.f / (1.f + __expf(-(gi[1] + gh[1])));
  const float ng = tanhf(gi[2] + rg * gh[2]);
  const float upd = (1.f - zg) * ng + zg * sp;

  float sm = upd, sq = upd * upd;
#pragma unroll
  for (int m = 1; m < 64; m <<= 1) { sm += __shfl_xor(sm, m); sq += __shfl_xor(sq, m); }
  const float mean = sm * (1.f / 64.f);
  const float var = sq * (1.f / 64.f) - mean * mean;
  uln_sh[l] = (upd - mean) * rsqrtf(var + 1e-5f) * g_mlp[l] + b_mlp[l];
  __syncthreads();

#pragma unroll
  for (int part = 0; part < 2; ++part) {
    const int j = part * 64 + l;
    float acc = b1[j];
    const float* w1 = W1 + j * 64;
    for (int k = 0; k < 64; ++k) acc += uln_sh[k] * w1[k];
    h_sh[j] = fmaxf(acc, 0.f);
  }
  __syncthreads();

  float acc = b2[l];
  const float* w2 = W2 + l * 128;
  for (int k = 0; k < 128; ++k) acc += h_sh[k] * w2[k];
  const float sv = upd + acc;
  out[(b * 8 + s) * 64 + l] = sv;

  if (make_q) {  // uniform branch
    float sm2 = sv, sq2 = sv * sv;
#pragma unroll
    for (int m = 1; m < 64; m <<= 1) { sm2 += __shfl_xor(sm2, m); sq2 += __shfl_xor(sq2, m); }
    const float mean2 = sm2 * (1.f / 64.f);
    const float var2 = sq2 * (1.f / 64.f) - mean2 * mean2;
    const float lnv = (sv - mean2) * rsqrtf(var2 + 1e-5f) * gs[l] + bsl[l];
    __syncthreads();
    u_sh[l] = lnv;
    __syncthreads();
    float qa = 0.f;
    const float* w = Wq + l * 64;
    for (int k = 0; k < 64; ++k) qa += u_sh[k] * w[k];
    qb[(b * 8 + s) * 64 + l] = (unsigned short)f2bf(qa * 0.125f);
  }
}

// ---------------------------------------------------------------------------
extern "C" void kernel_launch(void* const* d_in, const int* in_sizes, int n_in,
                              void* d_out, int out_size, void* d_ws, size_t ws_size,
                              hipStream_t stream) {
  const float* x       = (const float*)d_in[0];
  const float* noise   = (const float*)d_in[1];
  const float* mu      = (const float*)d_in[2];
  const float* lsig    = (const float*)d_in[3];
  const float* ln_in_g = (const float*)d_in[4];
  const float* ln_in_b = (const float*)d_in[5];
  const float* ln_sl_g = (const float*)d_in[6];
  const float* ln_sl_b = (const float*)d_in[7];
  const float* ln_ml_g = (const float*)d_in[8];
  const float* ln_ml_b = (const float*)d_in[9];
  const float* Wq      = (const float*)d_in[10];
  const float* Wk      = (const float*)d_in[11];
  const float* Wv      = (const float*)d_in[12];
  const float* W_ih    = (const float*)d_in[13];
  const float* W_hh    = (const float*)d_in[14];
  const float* b_ih    = (const float*)d_in[15];
  const float* b_hh    = (const float*)d_in[16];
  const float* W1      = (const float*)d_in[17];
  const float* b1      = (const float*)d_in[18];
  const float* W2      = (const float*)d_in[19];
  const float* b2      = (const float*)d_in[20];

  // ws: K bf16 (64MB) | Vt bf16 (64MB) | Wkb | Wvb | qb | slots | Wpart | cpart
  unsigned short* Kw  = (unsigned short*)d_ws;
  unsigned short* Vt  = Kw + (size_t)BB * NN * 64;
  unsigned short* Wkb = Vt + (size_t)BB * NN * 64;
  unsigned short* Wvb = Wkb + 4096;
  unsigned short* qb  = Wvb + 4096;
  float* slots = (float*)(qb + 16384);
  float* Wpart = slots + 32 * 8 * 64;
  float* cpart = Wpart + (size_t)1024 * 512;

  prep_kernel<<<dim3(16), dim3(256), 0, stream>>>(Wk, Wv, Wkb, Wvb);
  proj_kernel<<<dim3(2112), dim3(256), 0, stream>>>(
      x, ln_in_g, ln_in_b, Wkb, Wvb, Kw, Vt, noise, mu, lsig, slots);
  q_kernel<<<dim3(256), dim3(64), 0, stream>>>(slots, ln_sl_g, ln_sl_b, Wq, qb);

  for (int it = 0; it < 3; ++it) {
    reduce_kernel<<<dim3(1024), dim3(256), 0, stream>>>(Kw, Vt, qb, Wpart, cpart);
    update_kernel<<<dim3(256), dim3(64), 0, stream>>>(
        Wpart, cpart, slots, (it == 2) ? (float*)d_out : slots,
        W_ih, W_hh, b_ih, b_hh, ln_ml_g, ln_ml_b, W1, b1, W2, b2,
        ln_sl_g, ln_sl_b, Wq, qb, (it < 2) ? 1 : 0);
  }
}